// Round 4
// baseline (119.876 us; speedup 1.0000x reference)
//
#include <hip/hip_runtime.h>

typedef float f32x2 __attribute__((ext_vector_type(2)));
typedef float f32x4 __attribute__((ext_vector_type(4)));

#define PAD 3
#define HH 320
#define WW 1024
#define BB 8
#define TH 32
#define TW 64
#define HALO_H (TH + 2*PAD)   // 38
#define LDS_W  72             // 4 left halo + 64 + 4 right halo
#define NF4    (LDS_W/4)      // 18 float4 per staged row
#define NPOS   (HALO_H * NF4) // 684 float4 positions per plane
#define RPW 8                 // rows per wave (round-1 geometry: 4 waves x 8 rows)
#define NWAVES 4
#define NTHREADS (NWAVES * 64)

#define NIN ((HH - 2*PAD) * (WW - 2*PAD))
#define OUT_SCALE (1.0 / (49.0 * (double)BB * (double)HH * (double)WW))
#define C0 ((float)(48.0 * (double)BB * (double)NIN * OUT_SCALE))
#define NEG_SCALE ((float)(-0.1 * OUT_SCALE))

#define KEEP2(v) asm("" : "+v"(v))

static __device__ __forceinline__ f32x2 mk2(float a, float b){ f32x2 r; r.x=a; r.y=b; return r; }
static __device__ __forceinline__ f32x2 sp2(float a){ f32x2 r; r.x=a; r.y=a; return r; }

// Forced packed FP32 math (gfx90a+ dual-FP32 pipe; compiler scalarizes
// ext_vector float2 otherwise -- measured r0->r1: only 0.78x, not 0.55x).
static __device__ __forceinline__ f32x2 pk_add(f32x2 a, f32x2 b){
    f32x2 d; asm("v_pk_add_f32 %0, %1, %2" : "=v"(d) : "v"(a), "v"(b)); return d; }
static __device__ __forceinline__ f32x2 pk_mul(f32x2 a, f32x2 b){
    f32x2 d; asm("v_pk_mul_f32 %0, %1, %2" : "=v"(d) : "v"(a), "v"(b)); return d; }
static __device__ __forceinline__ f32x2 pk_fma(f32x2 a, f32x2 b, f32x2 c){
    f32x2 d; asm("v_pk_fma_f32 %0, %1, %2, %3" : "=v"(d) : "v"(a), "v"(b), "v"(c)); return d; }

// Two offsets at once. Exact algebra:
//   t^2 = s*(s*A - 2*dx*dy), s=rsq(ax*ay), A=dx^2*ay+dy^2*ax, a*=0.81+d*^2
//   w1/(0.1+t1^2)+w2/(0.1+t2^2) = rcp(b1*b2)*(w1*b2+w2*b1);  INTERIOR: w==2
template<bool INTERIOR>
static __device__ __forceinline__ void pair2(f32x2 nx, f32x2 ny,
    f32x2 mcx2, f32x2 mcy2, f32x2 c081, f32x2 cm2, f32x2 c01,
    f32x2 w2, float& acc)
{
    f32x2 dx  = pk_add(nx, mcx2);
    f32x2 dy  = pk_add(ny, mcy2);
    f32x2 dx2 = pk_mul(dx, dx);
    f32x2 dy2 = pk_mul(dy, dy);
    f32x2 ax  = pk_add(dx2, c081);
    f32x2 ay  = pk_add(dy2, c081);
    f32x2 P   = pk_mul(ax, ay);
    f32x2 s; s.x = __builtin_amdgcn_rsqf(P.x); s.y = __builtin_amdgcn_rsqf(P.y);
    f32x2 A   = pk_fma(dx2, ay, pk_mul(dy2, ax));
    f32x2 hm  = pk_mul(pk_mul(dx, dy), cm2);
    f32x2 t2  = pk_mul(s, pk_fma(s, A, hm));
    f32x2 den = pk_add(t2, c01);
    float ip  = __builtin_amdgcn_rcpf(den.x * den.y);
    float cross;
    if constexpr (INTERIOR) cross = den.x + den.y;
    else                    cross = fmaf(w2.x, den.y, w2.y * den.x);
    acc = fmaf(ip, cross, acc);
}

// load one staged row's dj-pair groups: A=(-3,-2) B=(-1,0) C=(+1,+2) D=+3
// adjacent-dword reads merge into ds_read2_b32 (8 LDS instrs/row, was 14)
#define LOADROW(ARR, ROW, P, S) do {                         \
    P[0].x = ARR[ROW][tx+1]; P[0].y = ARR[ROW][tx+2];        \
    P[1].x = ARR[ROW][tx+3]; P[1].y = ARR[ROW][tx+4];        \
    P[2].x = ARR[ROW][tx+5]; P[2].y = ARR[ROW][tx+6];        \
    S      = ARR[ROW][tx+7];                                 \
    KEEP2(P[0]); KEEP2(P[1]); KEEP2(P[2]);                   \
} while (0)

template<bool INTERIOR>
static __device__ __forceinline__ float compute_rows(
    const float (&sIx)[HALO_H][LDS_W], const float (&sIy)[HALO_H][LDS_W],
    int tile_i, int tile_j, int tx, int wv)
{
    const f32x2 c081 = sp2(0.81f);
    const f32x2 cm2  = sp2(-2.0f);
    const f32x2 c01  = sp2(0.1f);

    float cO3 = 0.0f;
    f32x2 cP0 = {}, cP1 = {}, cP2 = {}, cP3 = {};
    if constexpr (!INTERIOR) {
        float cO[7];
        const int gj = tile_j + tx;
        #pragma unroll
        for (int d = 0; d < 7; ++d) {
            int nj = gj + d - 3;
            cO[d] = (nj >= PAD && nj < WW - PAD) ? 1.0f : 0.0f;
        }
        cP0 = mk2(cO[0], cO[1]);
        cP1 = mk2(cO[2], cO[3]);
        cP2 = mk2(cO[4], cO[5]);
        cP3 = sp2(cO[6]);
        cO3 = cO[3];
    }

    const int li0 = wv * RPW;

    // rolling 4-row window as pair groups; slot k = pixel-row (li-li0) mod 4
    f32x2 px[4][3], py[4][3];
    float sx6[4], sy6[4];
    #pragma unroll
    for (int r = 0; r < 3; ++r) {
        LOADROW(sIx, li0 + 3 + r, px[r], sx6[r]);
        LOADROW(sIy, li0 + 3 + r, py[r], sy6[r]);
    }

    float acc = 0.0f;

    #pragma unroll 1
    for (int io = 0; io < RPW / 4; ++io) {
        #pragma unroll
        for (int iu = 0; iu < 4; ++iu) {
            const int li = li0 + io * 4 + iu;
            const int gi = tile_i + li;
            const int sn = (iu + 3) & 3;          // slot for incoming pixel-row li+3
            LOADROW(sIx, li + 6, px[sn], sx6[sn]);
            LOADROW(sIy, li + 6, py[sn], sy6[sn]);

            float rin[4] = {};
            f32x2 mc2 = {};
            if constexpr (!INTERIOR) {
                #pragma unroll
                for (int di = 0; di < 4; ++di) {
                    int ni = gi + di;
                    rin[di] = (ni >= PAD && ni < HH - PAD) ? 1.0f : 0.0f;
                }
                mc2 = sp2(rin[0] * cO3);
            }

            const int s0 = iu & 3, s1 = (iu+1)&3, s2 = (iu+2)&3, s3 = (iu+3)&3;
            const float cx = px[s0][1].y;          // dj=0 element = center
            const float cy = py[s0][1].y;
            const f32x2 mcx2 = sp2(-cx);
            const f32x2 mcy2 = sp2(-cy);

            // di = 0, dj = +1,+2  (group C of center row)
            pair2<INTERIOR>(px[s0][2], py[s0][2], mcx2, mcy2, c081, cm2, c01,
                INTERIOR ? c01 : pk_fma(sp2(rin[0]), cP2, mc2), acc);

            // di = 1..3: groups A, B, C
            #pragma unroll
            for (int di = 1; di <= 3; ++di) {
                const int s = (iu + di) & 3;
                const f32x2 rin2 = sp2(rin[di]);
                pair2<INTERIOR>(px[s][0], py[s][0], mcx2, mcy2, c081, cm2, c01,
                    INTERIOR ? c01 : pk_fma(rin2, cP0, mc2), acc);
                pair2<INTERIOR>(px[s][1], py[s][1], mcx2, mcy2, c081, cm2, c01,
                    INTERIOR ? c01 : pk_fma(rin2, cP1, mc2), acc);
                pair2<INTERIOR>(px[s][2], py[s][2], mcx2, mcy2, c081, cm2, c01,
                    INTERIOR ? c01 : pk_fma(rin2, cP2, mc2), acc);
            }

            // leftovers dj=+3 (group D), packed across di: (0,1) and (2,3)
            pair2<INTERIOR>(mk2(sx6[s0], sx6[s1]), mk2(sy6[s0], sy6[s1]),
                mcx2, mcy2, c081, cm2, c01,
                INTERIOR ? c01 : pk_fma(mk2(rin[0], rin[1]), cP3, mc2), acc);
            pair2<INTERIOR>(mk2(sx6[s2], sx6[s3]), mk2(sy6[s2], sy6[s3]),
                mcx2, mcy2, c081, cm2, c01,
                INTERIOR ? c01 : pk_fma(mk2(rin[2], rin[3]), cP3, mc2), acc);
        }
    }

    return acc;
}

__global__ __launch_bounds__(NTHREADS, 4) void ternary_loss_kernel(
    const float* __restrict__ x, const float* __restrict__ y,
    float* __restrict__ out)
{
    __shared__ __align__(16) float sIx[HALO_H][LDS_W];
    __shared__ __align__(16) float sIy[HALO_H][LDS_W];
    __shared__ float wave_sums[NWAVES];

    const int tile_j = blockIdx.x * TW;
    const int tile_i = blockIdx.y * TH;
    const int b      = blockIdx.z;
    const int tx  = threadIdx.x;            // 0..63
    const int wv  = threadIdx.y;            // 0..3
    const int tid = wv * 64 + tx;

    const size_t PLANE = (size_t)HH * WW;
    const float* xb = x + (size_t)b * 3 * PLANE;
    const float* yb = y + (size_t)b * 3 * PLANE;

    // ---- stage intensity halo tile into LDS with aligned float4 loads ----
    for (int p = tid; p < NPOS; p += NTHREADS) {
        int r  = p / NF4;
        int c4 = p - r * NF4;
        int gi  = tile_i - PAD + r;
        int gj0 = tile_j - 4 + 4 * c4;
        f32x4 vx = {0.0f, 0.0f, 0.0f, 0.0f};
        f32x4 vy = {0.0f, 0.0f, 0.0f, 0.0f};
        if ((unsigned)gi < (unsigned)HH && (unsigned)gj0 < (unsigned)WW) {
            const float* px = xb + (size_t)gi * WW + gj0;
            f32x4 a0 = *(const f32x4*)(px);
            f32x4 a1 = *(const f32x4*)(px + PLANE);
            f32x4 a2 = *(const f32x4*)(px + 2 * PLANE);
            vx = (a0 + a1 + a2) * (1.0f / 3.0f);
            const float* py = yb + (size_t)gi * WW + gj0;
            f32x4 b0 = *(const f32x4*)(py);
            f32x4 b1 = *(const f32x4*)(py + PLANE);
            f32x4 b2 = *(const f32x4*)(py + 2 * PLANE);
            vy = (b0 + b1 + b2) * (1.0f / 3.0f);
        }
        *(f32x4*)&sIx[r][4 * c4] = vx;
        *(f32x4*)&sIy[r][4 * c4] = vy;
    }
    __syncthreads();

    // block-uniform interior test (verified exact in r2/r3, absmax 0)
    const bool interior = (tile_i >= PAD) && (tile_i + TH + PAD <= HH - PAD)
                       && (tile_j >= 2*PAD) && (tile_j + TW + PAD <= WW - PAD);

    float acc;
    if (interior) acc = 2.0f * compute_rows<true >(sIx, sIy, tile_i, tile_j, tx, wv);
    else          acc =        compute_rows<false>(sIx, sIy, tile_i, tile_j, tx, wv);

    // ---- reduction: wave shuffle -> LDS across 4 waves -> one atomic ----
    #pragma unroll
    for (int off = 32; off > 0; off >>= 1)
        acc += __shfl_down(acc, off, 64);
    if (tx == 0) wave_sums[wv] = acc;
    __syncthreads();
    if (tid == 0) {
        float total = (wave_sums[0] + wave_sums[1] + wave_sums[2] + wave_sums[3]) * NEG_SCALE;
        if (blockIdx.x == 0 && blockIdx.y == 0 && blockIdx.z == 0)
            total += C0;                       // analytic  sum(w)*1  term, added once
        atomicAdd(out, total);
    }
}

extern "C" void kernel_launch(void* const* d_in, const int* in_sizes, int n_in,
                              void* d_out, int out_size, void* d_ws, size_t ws_size,
                              hipStream_t stream) {
    const float* x = (const float*)d_in[0];
    const float* y = (const float*)d_in[1];
    float* out = (float*)d_out;

    hipMemsetAsync(out, 0, sizeof(float), stream);

    dim3 grid(WW / TW, HH / TH, BB);   // 16 x 10 x 8 = 1280 blocks
    dim3 block(64, NWAVES, 1);
    ternary_loss_kernel<<<grid, block, 0, stream>>>(x, y, out);
}